// Round 1
// baseline (33.670 us; speedup 1.0000x reference)
//
#include <hip/hip_runtime.h>

// CustomLoss: fused 4-way reduction over N rows -> scalar loss.
// total = 10*mean((t-c)^2) + 0.1*mean(u-l) + 10*mean(max(l-u,0)) + 0.5*sum(dir)/N
// where c=(l+u)/2, dir = pv==0 ? relu(c-prev) : relu(prev-c).

constexpr int BLOCK = 256;
constexpr int GRID_MAX = 2048;

__device__ inline void block_reduce4(float& a, float& b, float& c, float& d) {
    // wave-64 shuffle reduce
    #pragma unroll
    for (int off = 32; off > 0; off >>= 1) {
        a += __shfl_down(a, off);
        b += __shfl_down(b, off);
        c += __shfl_down(c, off);
        d += __shfl_down(d, off);
    }
    __shared__ float s[4][BLOCK / 64];
    const int lane = threadIdx.x & 63;
    const int wid  = threadIdx.x >> 6;
    if (lane == 0) { s[0][wid] = a; s[1][wid] = b; s[2][wid] = c; s[3][wid] = d; }
    __syncthreads();
    if (threadIdx.x == 0) {
        #pragma unroll
        for (int w = 1; w < BLOCK / 64; ++w) {
            a += s[0][w]; b += s[1][w]; c += s[2][w]; d += s[3][w];
        }
    }
}

__global__ __launch_bounds__(BLOCK) void loss_partial(
    const float4* __restrict__ pred4,   // (N/4)*2 float4: [l0,u0,l1,u1],[l2,u2,l3,u3]
    const float4* __restrict__ tgt4,
    const float4* __restrict__ prev4,
    const int4*   __restrict__ pv4,
    const float*  __restrict__ pred,    // scalar tail access
    const float*  __restrict__ tgt,
    const float*  __restrict__ prev,
    const int*    __restrict__ pv,
    float4* __restrict__ partials,
    long long n, long long nthreads)
{
    const long long ngroups = n >> 2;
    const long long tid = (long long)blockIdx.x * BLOCK + threadIdx.x;

    float sc = 0.f, sw = 0.f, sv = 0.f, sd = 0.f;

    for (long long g = tid; g < ngroups; g += nthreads) {
        const float4 p0 = pred4[2 * g];
        const float4 p1 = pred4[2 * g + 1];
        const float4 t  = tgt4[g];
        const float4 pr = prev4[g];
        const int4   v  = pv4[g];

        const float l[4]  = { p0.x, p0.z, p1.x, p1.z };
        const float u[4]  = { p0.y, p0.w, p1.y, p1.w };
        const float tt[4] = { t.x, t.y, t.z, t.w };
        const float pp[4] = { pr.x, pr.y, pr.z, pr.w };
        const int   vv[4] = { v.x, v.y, v.z, v.w };

        #pragma unroll
        for (int j = 0; j < 4; ++j) {
            const float c = (l[j] + u[j]) * 0.5f;
            const float d = tt[j] - c;
            sc += d * d;
            sw += u[j] - l[j];
            sv += fmaxf(l[j] - u[j], 0.f);
            const float dif = (vv[j] == 0) ? (c - pp[j]) : (pp[j] - c);
            sd += fmaxf(dif, 0.f);
        }
    }

    // scalar tail (n % 4 leftovers)
    for (long long i = (ngroups << 2) + tid; i < n; i += nthreads) {
        const float lo = pred[2 * i];
        const float up = pred[2 * i + 1];
        const float c  = (lo + up) * 0.5f;
        const float d  = tgt[i] - c;
        sc += d * d;
        sw += up - lo;
        sv += fmaxf(lo - up, 0.f);
        const float dif = (pv[i] == 0) ? (c - prev[i]) : (prev[i] - c);
        sd += fmaxf(dif, 0.f);
    }

    block_reduce4(sc, sw, sv, sd);
    if (threadIdx.x == 0) {
        partials[blockIdx.x] = make_float4(sc, sw, sv, sd);
    }
}

__global__ __launch_bounds__(BLOCK) void loss_final(
    const float4* __restrict__ partials, int nparts,
    float* __restrict__ out, float inv_n)
{
    float sc = 0.f, sw = 0.f, sv = 0.f, sd = 0.f;
    for (int i = threadIdx.x; i < nparts; i += BLOCK) {
        const float4 p = partials[i];
        sc += p.x; sw += p.y; sv += p.z; sd += p.w;
    }
    block_reduce4(sc, sw, sv, sd);
    if (threadIdx.x == 0) {
        out[0] = 10.0f * sc * inv_n
               + 0.1f  * sw * inv_n
               + 10.0f * sv * inv_n
               + 0.5f  * sd * inv_n;
    }
}

extern "C" void kernel_launch(void* const* d_in, const int* in_sizes, int n_in,
                              void* d_out, int out_size, void* d_ws, size_t ws_size,
                              hipStream_t stream) {
    const float* pred = (const float*)d_in[0];   // (N,2) f32
    const float* tgt  = (const float*)d_in[1];   // (N,1) f32
    const float* prev = (const float*)d_in[2];   // (N,)  f32
    const int*   pv   = (const int*)d_in[3];     // (N,)  int (0/1)
    float*       out  = (float*)d_out;

    const long long n = (long long)in_sizes[2];  // prev_pci element count = N

    int grid = GRID_MAX;
    if (ws_size < (size_t)grid * sizeof(float4)) {
        grid = (int)(ws_size / sizeof(float4));
        if (grid < 1) grid = 1;
    }
    float4* partials = (float4*)d_ws;

    loss_partial<<<grid, BLOCK, 0, stream>>>(
        (const float4*)pred, (const float4*)tgt, (const float4*)prev, (const int4*)pv,
        pred, tgt, prev, pv,
        partials, n, (long long)grid * BLOCK);

    loss_final<<<1, BLOCK, 0, stream>>>(partials, grid, out, 1.0f / (float)n);
}